// Round 5
// baseline (34678.485 us; speedup 1.0000x reference)
//
#include <hip/hip_runtime.h>
#include <hip/hip_bf16.h>
#include <cstddef>
#include <cstdint>

// Problem dims (fixed): T=512, B=64, D=H=512, gates = 4*H = 2048
#define TT 512
#define BB 64
#define HH 512

typedef __attribute__((ext_vector_type(8))) short bf16x8;   // 8 bf16 = 4 VGPRs
typedef __attribute__((ext_vector_type(4))) float f32x4;    // MFMA C/D

__device__ __forceinline__ float sigf(float x) { return 1.0f / (1.0f + __expf(-x)); }

// fp32 -> bf16 (round-nearest-even), as raw short
__device__ __forceinline__ short f2bf(float x) {
  uint32_t u = __float_as_uint(x);
  u += 0x7FFFu + ((u >> 16) & 1u);
  return (short)(u >> 16);
}

// Adaptive 8-element fragment load (element-indexed). isbf: 1 = bf16, 0 = fp32.
__device__ __forceinline__ bf16x8 ldab(const void* base, size_t e, int isbf) {
  if (isbf) return *(const bf16x8*)((const short*)base + e);
  const float* f = (const float*)base + e;
  float4 a = *(const float4*)f;
  float4 b = *(const float4*)(f + 4);
  bf16x8 r;
  r[0] = f2bf(a.x); r[1] = f2bf(a.y); r[2] = f2bf(a.z); r[3] = f2bf(a.w);
  r[4] = f2bf(b.x); r[5] = f2bf(b.y); r[6] = f2bf(b.z); r[7] = f2bf(b.w);
  return r;
}

__device__ __forceinline__ float ldsc(const void* base, size_t e, int isbf) {
  if (isbf) return (float)((const __hip_bfloat16*)base)[e];
  return ((const float*)base)[e];
}

__device__ __forceinline__ void stsc(void* base, size_t e, float v, int isbf) {
  if (isbf) ((__hip_bfloat16*)base)[e] = __float2bfloat16(v);
  else      ((float*)base)[e] = v;
}

// ---------------------------------------------------------------------------
// Dtype sniffer: bits[14:7] of each 32-bit word = bf16 exponent of the low
// half if data is bf16 pairs (N(0,1) -> in [110,140] ~always), or fp32
// mantissa bits (uniform -> ~12% hit). 4096 words; flag = majority.
// ---------------------------------------------------------------------------
__global__ __launch_bounds__(256) void sniff(const unsigned int* __restrict__ x,
                                             int* __restrict__ flag) {
  __shared__ int cnt[256];
  int c = 0;
#pragma unroll
  for (int i = 0; i < 16; ++i) {
    unsigned w = x[threadIdx.x * 16 + i];
    unsigned e = (w >> 7) & 0xFFu;
    c += (e >= 110u && e <= 140u) ? 1 : 0;
  }
  cnt[threadIdx.x] = c;
  __syncthreads();
  for (int s = 128; s > 0; s >>= 1) {
    if ((int)threadIdx.x < s) cnt[threadIdx.x] += cnt[threadIdx.x + s];
    __syncthreads();
  }
  if (threadIdx.x == 0) flag[0] = (cnt[0] > 2048) ? 1 : 0;
}

// ---------------------------------------------------------------------------
// LAYER 0 step (both dirs, full batch). Grid 256 = dir(2) x jtile(32) x bt(4);
// 4 waves = 4 gates. h bf16 PRE-MASKED with consuming step's mask; c fp32 raw.
// ---------------------------------------------------------------------------
__global__ __launch_bounds__(256) void l0_step(
    const void* __restrict__ x,                 // [T][64][512]  (bf16 or fp32)
    const void* __restrict__ Wih_f,             // [2048][512]
    const void* __restrict__ Whh_f,             // [2048][512]
    const void* __restrict__ bias_f,            // [2048]
    const void* __restrict__ Wih_b,
    const void* __restrict__ Whh_b,
    const void* __restrict__ bias_b,
    const __hip_bfloat16* __restrict__ h_in,    // [2][64][512] bf16 internal
    __hip_bfloat16* __restrict__ h_out,
    float* __restrict__ c_st,                   // [2][64][512]
    const int* __restrict__ lens,
    void* __restrict__ out,                     // [T][64][1024]
    const int* __restrict__ flagp,
    int s)
{
  const int isbf = flagp[0];
  const int bx = blockIdx.x;
  const int d  = bx >> 7;
  const int jt = (bx >> 2) & 31;
  const int bt = bx & 3;
  const int j0 = jt * 16;
  const int b0 = bt * 16;
  const int t_eff = d ? (TT - 1 - s) : s;

  const void* Wih  = d ? Wih_b  : Wih_f;
  const void* Whh  = d ? Whh_b  : Whh_f;
  const void* bias = d ? bias_b : bias_f;

  const int tid  = threadIdx.x;
  const int lane = tid & 63;
  const int g    = tid >> 6;          // wave = gate (i,f,g,o)
  const int nm   = lane & 15;
  const int kq   = (lane >> 4) * 8;

  const size_t aoff1 = (size_t)(g * HH + j0 + nm) * HH + kq;          // Wih row
  const size_t boff1 = ((size_t)t_eff * BB + (b0 + nm)) * HH + kq;    // x row
  const size_t aoff2 = aoff1;                                          // Whh row
  const __hip_bfloat16* brow2 = h_in + (size_t)(d * BB + b0 + nm) * HH + kq;

  f32x4 acc = {0.f, 0.f, 0.f, 0.f};
#pragma unroll 4
  for (int k = 0; k < HH; k += 32)
    acc = __builtin_amdgcn_mfma_f32_16x16x32_bf16(ldab(Wih, aoff1 + k, isbf),
                                                  ldab(x, boff1 + k, isbf), acc, 0, 0, 0);
#pragma unroll 4
  for (int k = 0; k < HH; k += 32)
    acc = __builtin_amdgcn_mfma_f32_16x16x32_bf16(ldab(Whh, aoff2 + k, isbf),
                                                  ldab(brow2 + k, 0, 1), acc, 0, 0, 0);

  __shared__ float gx[4][16][17];
  {
    const int quad = lane >> 4;
#pragma unroll
    for (int r = 0; r < 4; ++r)
      gx[g][quad * 4 + r][nm] = acc[r];
  }
  __syncthreads();

  const int jj = tid & 15;
  const int bb = tid >> 4;
  const int j  = j0 + jj;
  const int b  = b0 + bb;

  float gi = gx[0][jj][bb] + ldsc(bias, 0 * HH + j, isbf);
  float gf = gx[1][jj][bb] + ldsc(bias, 1 * HH + j, isbf);
  float gg = gx[2][jj][bb] + ldsc(bias, 2 * HH + j, isbf);
  float go = gx[3][jj][bb] + ldsc(bias, 3 * HH + j, isbf);

  const int len = lens[b];
  const float m = (t_eff < len) ? 1.0f : 0.0f;
  const int tn = d ? (t_eff - 1) : (t_eff + 1);
  const float mn = (tn >= 0 && tn < len) ? 1.0f : 0.0f;

  const int ci = (d * BB + b) * HH + j;
  const float cold = c_st[ci] * m;
  const float c2 = sigf(gf) * cold + sigf(gi) * tanhf(gg);
  const float h2 = sigf(go) * tanhf(c2);
  c_st[ci] = c2;
  h_out[ci] = __float2bfloat16(h2 * mn);
  stsc(out, ((size_t)t_eff * BB + b) * 1024 + (size_t)d * HH + j, h2 * m, isbf);
}

// ---------------------------------------------------------------------------
// Stash copy (one layer-1 batch pass): snapshot hazard halves of this pass's
// b-columns from pristine y0 (in out) into bf16 stash.
// ---------------------------------------------------------------------------
__global__ __launch_bounds__(256) void stash_copy(
    const void* __restrict__ out,
    __hip_bfloat16* __restrict__ stashF,
    __hip_bfloat16* __restrict__ stashB,
    const int* __restrict__ flagp,
    int bcount, int pass_off)
{
  const int isbf = flagp[0];
  const size_t idx = ((size_t)blockIdx.x * 256 + threadIdx.x) * 8;
  const int k = (int)(idx & 511);
  const size_t r = idx >> 9;
  const int lb = (int)(r % bcount);
  const size_t rr = r / bcount;       // 0..511; <256 -> F, else B
  const int row = (int)(rr & 255);
  const bool isB = rr >= 256;

  const size_t src = ((size_t)(isB ? (256 + row) : row) * BB + pass_off + lb) * 1024 +
                     (isB ? HH : 0) + k;
  bf16x8 v = ldab(out, src, isbf);
  __hip_bfloat16* dst = (isB ? stashB : stashF) + ((size_t)row * bcount + lb) * HH + k;
  *(bf16x8*)(void*)dst = v;
}

// ---------------------------------------------------------------------------
// LAYER 1 kernel A: gate pre-activations G[d][g*512+j][lb] (fp32).
// Each per-dir input half: (base, elem-offset, stride, kind). kind 1 = stash
// (always bf16), kind 0 = out (follows global dtype flag).
// ---------------------------------------------------------------------------
__global__ __launch_bounds__(256) void l1_gates(
    const void* __restrict__ Wih_f,   // [2048][1024]
    const void* __restrict__ Whh_f,   // [2048][512]
    const void* __restrict__ Wih_b,
    const void* __restrict__ Whh_b,
    const void* __restrict__ f_lo, size_t f_lo_o, int f_lo_st, int f_lo_k,
    const void* __restrict__ f_hi, size_t f_hi_o, int f_hi_st, int f_hi_k,
    const void* __restrict__ b_lo, size_t b_lo_o, int b_lo_st, int b_lo_k,
    const void* __restrict__ b_hi, size_t b_hi_o, int b_hi_st, int b_hi_k,
    const __hip_bfloat16* __restrict__ h_in,    // pre-offset by pass_off*512
    float* __restrict__ G,                      // [2][2048][bcount]
    const int* __restrict__ flagp,
    int bcount)
{
  const int isbf = flagp[0];
  const int nbt = bcount >> 4;
  const int bx = blockIdx.x;
  const int d  = bx / (32 * nbt);
  const int rem = bx % (32 * nbt);
  const int jt = rem / nbt;
  const int bt = rem % nbt;
  const int j0 = jt * 16;
  const int b0 = bt * 16;                       // local b base

  const void* Wih = d ? Wih_b : Wih_f;
  const void* Whh = d ? Whh_b : Whh_f;
  const void* xlo = d ? b_lo : f_lo;
  const void* xhi = d ? b_hi : f_hi;
  const size_t olo = d ? b_lo_o : f_lo_o;
  const size_t ohi = d ? b_hi_o : f_hi_o;
  const int slo = d ? b_lo_st : f_lo_st;
  const int shi = d ? b_hi_st : f_hi_st;
  const int elo = (d ? b_lo_k : f_lo_k) ? 1 : isbf;
  const int ehi = (d ? b_hi_k : f_hi_k) ? 1 : isbf;

  const int tid  = threadIdx.x;
  const int lane = tid & 63;
  const int g    = tid >> 6;
  const int nm   = lane & 15;
  const int kq   = (lane >> 4) * 8;

  const size_t aoff  = (size_t)(g * HH + j0 + nm) * 1024 + kq;   // Wih row
  const size_t aoff2 = (size_t)(g * HH + j0 + nm) * HH + kq;     // Whh row
  const size_t bloff = olo + (size_t)(b0 + nm) * slo + kq;
  const size_t bhoff = ohi + (size_t)(b0 + nm) * shi + kq;
  const __hip_bfloat16* bh = h_in + (size_t)(d * BB + b0 + nm) * HH + kq;

  f32x4 acc = {0.f, 0.f, 0.f, 0.f};
#pragma unroll 4
  for (int k = 0; k < HH; k += 32)
    acc = __builtin_amdgcn_mfma_f32_16x16x32_bf16(ldab(Wih, aoff + k, isbf),
                                                  ldab(xlo, bloff + k, elo), acc, 0, 0, 0);
#pragma unroll 4
  for (int k = 0; k < HH; k += 32)
    acc = __builtin_amdgcn_mfma_f32_16x16x32_bf16(ldab(Wih, aoff + HH + k, isbf),
                                                  ldab(xhi, bhoff + k, ehi), acc, 0, 0, 0);
#pragma unroll 4
  for (int k = 0; k < HH; k += 32)
    acc = __builtin_amdgcn_mfma_f32_16x16x32_bf16(ldab(Whh, aoff2 + k, isbf),
                                                  ldab(bh + k, 0, 1), acc, 0, 0, 0);

  float* gp = G + ((size_t)d * 2048 + g * HH + j0 + (lane >> 4) * 4) * bcount + b0 + nm;
  gp[0 * (size_t)bcount] = acc[0];
  gp[1 * (size_t)bcount] = acc[1];
  gp[2 * (size_t)bcount] = acc[2];
  gp[3 * (size_t)bcount] = acc[3];
}

// ---------------------------------------------------------------------------
// LAYER 1 kernel B: nonlinearity + state update + in-place out write.
// ---------------------------------------------------------------------------
__global__ __launch_bounds__(256) void l1_update(
    const float* __restrict__ G,                // [2][2048][bcount]
    const void* __restrict__ bias_f,
    const void* __restrict__ bias_b,
    __hip_bfloat16* __restrict__ h_out,         // [2][64][512] (absolute b)
    float* __restrict__ c_st,                   // [2][64][512]
    const int* __restrict__ lens,
    void* __restrict__ out,
    const int* __restrict__ flagp,
    int s, int log2bc, int pass_off)
{
  const int isbf = flagp[0];
  const int bcount = 1 << log2bc;
  const int lin = blockIdx.x * 256 + threadIdx.x;
  const int lb = lin & (bcount - 1);
  const int j = (lin >> log2bc) & 511;
  const int d = lin >> (log2bc + 9);
  const int b = pass_off + lb;
  const void* bias = d ? bias_b : bias_f;

  const size_t gb = (size_t)d * 2048;
  float gi = G[(gb + 0 * HH + j) * bcount + lb] + ldsc(bias, 0 * HH + j, isbf);
  float gf = G[(gb + 1 * HH + j) * bcount + lb] + ldsc(bias, 1 * HH + j, isbf);
  float gg = G[(gb + 2 * HH + j) * bcount + lb] + ldsc(bias, 2 * HH + j, isbf);
  float go = G[(gb + 3 * HH + j) * bcount + lb] + ldsc(bias, 3 * HH + j, isbf);

  const int t_eff = d ? (TT - 1 - s) : s;
  const int len = lens[b];
  const float m = (t_eff < len) ? 1.0f : 0.0f;
  const int tn = d ? (t_eff - 1) : (t_eff + 1);
  const float mn = (tn >= 0 && tn < len) ? 1.0f : 0.0f;

  const int ci = (d * BB + b) * HH + j;
  const float cold = c_st[ci] * m;
  const float c2 = sigf(gf) * cold + sigf(gi) * tanhf(gg);
  const float h2 = sigf(go) * tanhf(c2);
  c_st[ci] = c2;
  h_out[ci] = __float2bfloat16(h2 * mn);
  stsc(out, ((size_t)t_eff * BB + b) * 1024 + (size_t)d * HH + j, h2 * m, isbf);
}

// ---------------------------------------------------------------------------
extern "C" void kernel_launch(void* const* d_in, const int* in_sizes, int n_in,
                              void* d_out, int out_size, void* d_ws, size_t ws_size,
                              hipStream_t stream) {
  (void)in_sizes; (void)n_in; (void)out_size;
  const void* x     = d_in[0];
  const int*  lens  = (const int*)d_in[1];
  const void* fWih0 = d_in[2];
  const void* fWhh0 = d_in[3];
  const void* fb0   = d_in[4];
  const void* bWih0 = d_in[5];
  const void* bWhh0 = d_in[6];
  const void* bb0   = d_in[7];
  const void* fWih1 = d_in[8];
  const void* fWhh1 = d_in[9];
  const void* fb1   = d_in[10];
  const void* bWih1 = d_in[11];
  const void* bWhh1 = d_in[12];
  const void* bb1   = d_in[13];
  void* out = d_out;

  // --- choose batch-pass count P from ws_size ---
  // need(P) = 256 (flag) + stash 2*256*(64/P)*512*2 + G 2*2048*(64/P)*4 + h/c 512K
  const size_t STATE = (size_t)(2 * 2 * BB * HH) * 2 + (size_t)(2 * BB * HH) * 4;
  int P = 4, log2bc = 4;
  {
    const size_t need1 = 256 + (size_t)2 * 256 * 64 * HH * 2 + (size_t)2 * 2048 * 64 * 4 + STATE;
    const size_t need2 = 256 + (size_t)2 * 256 * 32 * HH * 2 + (size_t)2 * 2048 * 32 * 4 + STATE;
    if (ws_size >= need1)      { P = 1; log2bc = 6; }
    else if (ws_size >= need2) { P = 2; log2bc = 5; }
  }
  const int bcount = 64 / P;

  // --- ws layout: [flag 256B][stashF][stashB][G][hbuf][cbuf] ---
  int* flagp = (int*)d_ws;
  const size_t HALF_E = (size_t)256 * bcount * HH;
  __hip_bfloat16* stashF = (__hip_bfloat16*)((char*)d_ws + 256);
  __hip_bfloat16* stashB = stashF + HALF_E;
  float* G = (float*)(stashB + HALF_E);
  __hip_bfloat16* hbuf = (__hip_bfloat16*)(G + (size_t)2 * 2048 * bcount);
  const size_t HPAR = (size_t)2 * BB * HH;
  float* cbuf = (float*)(hbuf + 2 * HPAR);
  const size_t ZERO_BYTES = 2 * HPAR * sizeof(__hip_bfloat16) +
                            (size_t)2 * BB * HH * sizeof(float);

  // ---- dtype sniff ----
  sniff<<<1, 256, 0, stream>>>((const unsigned int*)x, flagp);

  // ---- layer 0: x -> out (full batch) ----
  hipMemsetAsync(hbuf, 0, ZERO_BYTES, stream);
  for (int s = 0; s < TT; ++s) {
    const __hip_bfloat16* hin = hbuf + (size_t)(s & 1) * HPAR;
    __hip_bfloat16* hout      = hbuf + (size_t)((s + 1) & 1) * HPAR;
    l0_step<<<256, 256, 0, stream>>>(x, fWih0, fWhh0, fb0, bWih0, bWhh0, bb0,
                                     hin, hout, cbuf, lens, out, flagp, s);
  }

  // ---- layer 1: P batch passes, in-place over out ----
  for (int p = 0; p < P; ++p) {
    const int pass_off = p * bcount;
    stash_copy<<<128 * bcount, 256, 0, stream>>>(out, stashF, stashB, flagp, bcount, pass_off);
    hipMemsetAsync(hbuf, 0, ZERO_BYTES, stream);
    for (int s = 0; s < TT; ++s) {
      const __hip_bfloat16* hin = hbuf + (size_t)(s & 1) * HPAR;
      __hip_bfloat16* hout      = hbuf + (size_t)((s + 1) & 1) * HPAR;
      const int tb = TT - 1 - s;

      // fwd reads row s: lo always pristine in out; hi from stashB when s>=256.
      const void* f_lo = out;
      size_t f_lo_o = ((size_t)s * BB + pass_off) * 1024;
      int f_lo_st = 1024, f_lo_k = 0;
      const void* f_hi; size_t f_hi_o; int f_hi_st, f_hi_k;
      if (s < 256) { f_hi = out; f_hi_o = f_lo_o + HH; f_hi_st = 1024; f_hi_k = 0; }
      else         { f_hi = stashB; f_hi_o = (size_t)(s - 256) * bcount * HH; f_hi_st = HH; f_hi_k = 1; }
      // bwd reads row tb: hi always pristine; lo from stashF when s>=256.
      const void* b_hi = out;
      size_t b_hi_o = ((size_t)tb * BB + pass_off) * 1024 + HH;
      int b_hi_st = 1024, b_hi_k = 0;
      const void* b_lo; size_t b_lo_o; int b_lo_st, b_lo_k;
      if (s < 256) { b_lo = out; b_lo_o = ((size_t)tb * BB + pass_off) * 1024; b_lo_st = 1024; b_lo_k = 0; }
      else         { b_lo = stashF; b_lo_o = (size_t)tb * bcount * HH; b_lo_st = HH; b_lo_k = 1; }

      l1_gates<<<2 * 32 * (bcount / 16), 256, 0, stream>>>(
          fWih1, fWhh1, bWih1, bWhh1,
          f_lo, f_lo_o, f_lo_st, f_lo_k,
          f_hi, f_hi_o, f_hi_st, f_hi_k,
          b_lo, b_lo_o, b_lo_st, b_lo_k,
          b_hi, b_hi_o, b_hi_st, b_hi_k,
          hin + (size_t)pass_off * HH, G, flagp, bcount);
      l1_update<<<4 * bcount, 256, 0, stream>>>(G, fb1, bb1, hout, cbuf, lens, out,
                                                flagp, s, log2bc, pass_off);
    }
  }
}